// Round 1
// baseline (272.422 us; speedup 1.0000x reference)
//
#include <hip/hip_runtime.h>
#include <hip/hip_bf16.h>
#include <cstdint>

// Problem: out[s,b,m,n] = sum_k (x[s,b,m,k]-XZ)*XS * (y[b,k,n]-YZ)*YS
// S=7 B=8 M=K=N=1024.  XZ=-66, XS=0.03, YZ=160, YS=0.025.
// Affine decomposition with y' = y-128 (both x,y' exact in bf16):
//   out = XS*YS * ( S' - 32*Rx[m] + 66*Cy[n] - 10813440 ),  S' = sum x*y'
// Integer-exact in fp32 accumulation (all partials << 2^24).

#define MD 1024
#define KD 1024
#define ND 1024
#define NG 56   // 7*8 gemms

typedef __bf16 bf16x8 __attribute__((ext_vector_type(8)));
typedef float  f32x4  __attribute__((ext_vector_type(4)));

__device__ __forceinline__ unsigned short bfb(float f) {
    // exact for integer-valued floats with |v| <= 255 (<=8 significand bits)
    return (unsigned short)(__float_as_uint(f) >> 16);
}

#define GLOAD16(g, l) __builtin_amdgcn_global_load_lds( \
    (const __attribute__((address_space(1))) void*)(g), \
    (__attribute__((address_space(3))) void*)(l), 16, 0, 0)

// ---- prepass 1: x (fp32 int values) -> bf16 + row sums. one wave per row ----
__global__ __launch_bounds__(256) void k_prep_x(const float* __restrict__ x,
                                                unsigned short* __restrict__ xb,
                                                float* __restrict__ rx, int writeB) {
    int row  = blockIdx.x * 4 + (threadIdx.x >> 6);   // 57344 rows total
    int lane = threadIdx.x & 63;
    const float* src = x + (size_t)row * KD;
    float s = 0.f;
#pragma unroll
    for (int it = 0; it < 4; ++it) {
        float4 v = *(const float4*)(src + it * 256 + lane * 4);
        s += (v.x + v.y) + (v.z + v.w);
        if (writeB) {
            ushort4 o;
            o.x = bfb(v.x); o.y = bfb(v.y); o.z = bfb(v.z); o.w = bfb(v.w);
            *(ushort4*)(xb + (size_t)row * KD + it * 256 + lane * 4) = o;
        }
    }
#pragma unroll
    for (int off = 32; off > 0; off >>= 1) s += __shfl_down(s, off);
    if (lane == 0) rx[row] = s;
}

// ---- prepass 2: y -> transposed bf16 y_t[b][n][k] = bf16(y-128), + col sums ----
__global__ __launch_bounds__(256) void k_prep_y(const float* __restrict__ y,
                                                unsigned short* __restrict__ yt,
                                                float* __restrict__ cy) {
    __shared__ float tile[64][65];
    __shared__ float csum[4][64];
    int b  = blockIdx.x >> 8;
    int t  = blockIdx.x & 255;
    int kt = (t >> 4) * 64, nt = (t & 15) * 64;
    int tx = threadIdx.x & 63;   // n within tile on read, k on write
    int ty = threadIdx.x >> 6;
    const float* src = y + ((size_t)b << 20) + (size_t)kt * 1024 + nt;
    float part = 0.f;
#pragma unroll
    for (int r = 0; r < 16; ++r) {
        int kk = r * 4 + ty;
        float v = src[(size_t)kk * 1024 + tx];
        tile[kk][tx] = v;
        part += v;
    }
    csum[ty][tx] = part;
    __syncthreads();
    if (threadIdx.x < 64) {
        float s = csum[0][tx] + csum[1][tx] + csum[2][tx] + csum[3][tx];
        atomicAdd(&cy[b * 1024 + nt + tx], s);   // exact: integer sums < 2^24
    }
#pragma unroll
    for (int r = 0; r < 16; ++r) {
        int nn = r * 4 + ty;
        float v = tile[tx][nn];
        yt[((size_t)b << 20) + (size_t)(nt + nn) * 1024 + kt + tx] = bfb(v - 128.0f);
    }
}

// ---- main GEMM: 128x128 tile, 4 waves, BK=32, m97-style ----
template <int FUSEDA>
__global__ __launch_bounds__(256) void k_gemm(const float* __restrict__ xf,
                                              const unsigned short* __restrict__ xb,
                                              const unsigned short* __restrict__ yt,
                                              const float* __restrict__ rx,
                                              const float* __restrict__ cy,
                                              float* __restrict__ out) {
    __shared__ __align__(16) unsigned short As[128 * 32];
    __shared__ __align__(16) unsigned short Bs[128 * 32];

    // bijective XCD swizzle (3584 % 8 == 0)
    int bid = blockIdx.x;
    int wg  = (bid & 7) * (NG * 64 / 8) + (bid >> 3);
    int g   = wg >> 6;
    int t   = wg & 63;
    int m0  = (t >> 3) * 128, n0 = (t & 7) * 128;
    int b   = g & 7;

    int tid  = threadIdx.x;
    int lane = tid & 63, w = tid >> 6;
    int wm = w >> 1, wn = w & 1;
    int lrow = lane & 15, lko = (lane >> 4) * 8;

    f32x4 acc[4][4];
#pragma unroll
    for (int i = 0; i < 4; ++i)
#pragma unroll
        for (int j = 0; j < 4; ++j) acc[i][j] = (f32x4){0.f, 0.f, 0.f, 0.f};

    const unsigned short* Ab = xb + (size_t)g * (MD * KD) + (size_t)m0 * KD;
    const float*          Af = xf + (size_t)g * (MD * KD) + (size_t)m0 * KD;
    const unsigned short* Bb = yt + (size_t)b * (ND * KD) + (size_t)n0 * KD;

    for (int kt = 0; kt < KD / 32; ++kt) {
        if constexpr (FUSEDA) {
            // reg-stage A: fp32 -> bf16 -> ds_write_b128
#pragma unroll
            for (int r = 0; r < 2; ++r) {
                int c = r * 256 + tid;
                int row = c >> 2, ko = (c & 3) * 8;
                const float* p = Af + (size_t)row * KD + kt * 32 + ko;
                float4 v0 = *(const float4*)p;
                float4 v1 = *(const float4*)(p + 4);
                uint4 pk;
                pk.x = (unsigned)bfb(v0.x) | ((unsigned)bfb(v0.y) << 16);
                pk.y = (unsigned)bfb(v0.z) | ((unsigned)bfb(v0.w) << 16);
                pk.z = (unsigned)bfb(v1.x) | ((unsigned)bfb(v1.y) << 16);
                pk.w = (unsigned)bfb(v1.z) | ((unsigned)bfb(v1.w) << 16);
                *(uint4*)&As[(size_t)c * 8] = pk;
            }
        } else {
#pragma unroll
            for (int r = 0; r < 2; ++r) {
                int c = r * 256 + tid;
                int row = c >> 2, ko = (c & 3) * 8;
                GLOAD16(Ab + (size_t)row * KD + kt * 32 + ko,
                        &As[(size_t)(r * 256 + (tid & ~63)) * 8]);
            }
        }
#pragma unroll
        for (int r = 0; r < 2; ++r) {
            int c = r * 256 + tid;
            int row = c >> 2, ko = (c & 3) * 8;
            GLOAD16(Bb + (size_t)row * KD + kt * 32 + ko,
                    &Bs[(size_t)(r * 256 + (tid & ~63)) * 8]);
        }
        asm volatile("s_waitcnt vmcnt(0)" ::: "memory");
        __syncthreads();

        bf16x8 a[4], bv[4];
#pragma unroll
        for (int f = 0; f < 4; ++f)
            a[f] = *(const bf16x8*)&As[(wm * 64 + f * 16 + lrow) * 32 + lko];
#pragma unroll
        for (int f = 0; f < 4; ++f)
            bv[f] = *(const bf16x8*)&Bs[(wn * 64 + f * 16 + lrow) * 32 + lko];
#pragma unroll
        for (int i = 0; i < 4; ++i)
#pragma unroll
            for (int j = 0; j < 4; ++j)
                acc[i][j] = __builtin_amdgcn_mfma_f32_16x16x32_bf16(a[i], bv[j], acc[i][j], 0, 0, 0);
        __syncthreads();
    }

    // epilogue: out = SC*(S' - 32*Rx + 66*Cy - 10813440)
    const float* rxg = rx + g * MD + m0 + wm * 64;
    const float* cyg = cy + b * ND + n0 + wn * 64;
    float* og = out + (size_t)g * (MD * ND) + (size_t)(m0 + wm * 64) * ND + (n0 + wn * 64);
    const float SC = 7.5e-4f;  // 0.03 * 0.025
#pragma unroll
    for (int i = 0; i < 4; ++i) {
#pragma unroll
        for (int j = 0; j < 4; ++j) {
            int coll = j * 16 + lrow;
            float cv = cyg[coll];
            f32x4 v = acc[i][j];
#pragma unroll
            for (int q = 0; q < 4; ++q) {
                int rowl = i * 16 + (lane >> 4) * 4 + q;
                float o = SC * (v[q] - 32.0f * rxg[rowl] + 66.0f * cv - 10813440.0f);
                og[(size_t)rowl * ND + coll] = o;
            }
        }
    }
}

// ---- emergency fallback: naive tiled fp32 (only if ws is tiny) ----
__global__ void k_naive(const float* __restrict__ x, const float* __restrict__ y,
                        float* __restrict__ out) {
    int g = blockIdx.z, b = g & 7;
    int tx = threadIdx.x, ty = threadIdx.y;
    int m = blockIdx.y * 16 + ty, n = blockIdx.x * 16 + tx;
    __shared__ float a[16][17], bs[16][17];
    float s = 0.f;
    for (int kt = 0; kt < 64; ++kt) {
        a[ty][tx]  = x[(size_t)g * 1048576 + (size_t)m * 1024 + kt * 16 + tx];
        bs[ty][tx] = y[(size_t)b * 1048576 + (size_t)(kt * 16 + ty) * 1024 + n];
        __syncthreads();
#pragma unroll
        for (int j = 0; j < 16; ++j)
            s += ((a[ty][j] + 66.0f) * 0.03f) * ((bs[j][tx] - 160.0f) * 0.025f);
        __syncthreads();
    }
    out[(size_t)g * 1048576 + (size_t)m * 1024 + n] = s;
}

extern "C" void kernel_launch(void* const* d_in, const int* in_sizes, int n_in,
                              void* d_out, int out_size, void* d_ws, size_t ws_size,
                              hipStream_t stream) {
    const float* x = (const float*)d_in[0];
    const float* y = (const float*)d_in[1];
    float* out = (float*)d_out;

    const size_t CY_OFF = 0;                    // 8*1024*4      = 32768
    const size_t RX_OFF = 32768;                // 56*1024*4     = 229376
    const size_t YT_OFF = 262144;               // 8*1024*1024*2 = 16777216
    const size_t XB_OFF = 262144 + 16777216;    // 56*1024*1024*2= 117440512
    const size_t NEED_BASE = XB_OFF;
    const size_t NEED_FULL = XB_OFF + 117440512ull;

    if (ws_size >= NEED_BASE) {
        float* cy          = (float*)((char*)d_ws + CY_OFF);
        float* rx          = (float*)((char*)d_ws + RX_OFF);
        unsigned short* yt = (unsigned short*)((char*)d_ws + YT_OFF);
        unsigned short* xb = (unsigned short*)((char*)d_ws + XB_OFF);
        int full = (ws_size >= NEED_FULL) ? 1 : 0;

        hipMemsetAsync(cy, 0, 32768, stream);
        k_prep_x<<<14336, 256, 0, stream>>>(x, xb, rx, full);
        k_prep_y<<<2048, 256, 0, stream>>>(y, yt, cy);
        if (full) k_gemm<0><<<NG * 64, 256, 0, stream>>>(x, xb, yt, rx, cy, out);
        else      k_gemm<1><<<NG * 64, 256, 0, stream>>>(x, xb, yt, rx, cy, out);
    } else {
        dim3 grid(64, 64, NG), blk(16, 16);
        k_naive<<<grid, blk, 0, stream>>>(x, y, out);
    }
}